// Round 15
// baseline (426.767 us; speedup 1.0000x reference)
//
#include <hip/hip_runtime.h>

#define ALPHA 0.1f
#define FIN 128
#define HD 64
#define TD 10
#define SCAN_ELEMS 1024
#define CHUNK 8192            // nodes per LDS chunk (2^13)
#define CSHIFT 13
#define SPLIT 32              // edge-slices per chunk

typedef __attribute__((ext_vector_type(8))) short short8v;   // 8 bf16 (4 VGPRs)
typedef __attribute__((ext_vector_type(4))) float f32x4;

__device__ __forceinline__ unsigned short f2bf(float f) {    // RNE f32->bf16
    unsigned u = __float_as_uint(f);
    return (unsigned short)((u + 0x7FFFu + ((u >> 16) & 1u)) >> 16);
}
__device__ __forceinline__ unsigned pack2(float a, float b) {
    return (unsigned)f2bf(a) | ((unsigned)f2bf(b) << 16);
}
__device__ __forceinline__ float bf2f(unsigned short u) {
    return __uint_as_float((unsigned)u << 16);
}

// ------- convert W1/W2 -> transposed bf16 tables; also init tmax -------
__global__ __launch_bounds__(256) void k_cvtW(const float* __restrict__ W1,
                                              const float* __restrict__ W2,
                                              unsigned short* __restrict__ W1t,
                                              unsigned short* __restrict__ W2t,
                                              unsigned* tmaxb) {
    int t = blockIdx.x * 256 + threadIdx.x;
    if (t == 0) *tmaxb = 0u;
    if (t < FIN * HD) {                       // 8192
        int c = t >> 7, k = t & 127;
        W1t[t] = f2bf(W1[k * HD + c]);
    }
    if (t < HD * HD) {                        // 4096
        int c = t >> 6, k = t & 63;
        W2t[t] = f2bf(W2[k * HD + c]);
    }
}

// ---------------- max(edge_time): block-reduced, 1 atomic per block ----------------
__global__ __launch_bounds__(256) void k_tmax(const float* __restrict__ t, unsigned* tmaxb, int E) {
    __shared__ unsigned sm[4];
    unsigned m = 0u;
    for (int i = blockIdx.x * 256 + threadIdx.x; i < E; i += gridDim.x * 256)
        m = max(m, __float_as_uint(t[i]));
    #pragma unroll
    for (int off = 32; off > 0; off >>= 1)
        m = max(m, (unsigned)__shfl_down((int)m, off, 64));
    if ((threadIdx.x & 63) == 0) sm[threadIdx.x >> 6] = m;
    __syncthreads();
    if (threadIdx.x == 0) {
        m = max(max(sm[0], sm[1]), max(sm[2], sm[3]));
        atomicMax(tmaxb, m);
    }
}

// ------ chunked LDS-privatized deg(row,decay-weighted) + hist(col) ------
__global__ __launch_bounds__(1024) void k_deghist(const int* __restrict__ ei,
                                                  const float* __restrict__ t,
                                                  const unsigned* __restrict__ tmaxb,
                                                  float* __restrict__ ebuf,
                                                  float* __restrict__ privD,
                                                  unsigned short* __restrict__ privH,
                                                  int E, int N) {
    __shared__ float ldsD[CHUNK];   // 32 KiB
    __shared__ int   ldsH[CHUNK];   // 32 KiB
    int c = blockIdx.x / SPLIT;
    int b = blockIdx.x - c * SPLIT;
    int base = c * CHUNK;
    for (int i = threadIdx.x; i < CHUNK; i += 1024) { ldsD[i] = 0.f; ldsH[i] = 0; }
    __syncthreads();
    float tmax = __uint_as_float(*tmaxb);
    long long e0 = (long long)E * b / SPLIT;
    long long e1 = (long long)E * (b + 1) / SPLIT;
    for (long long e = e0 + threadIdx.x; e < e1; e += 1024) {
        int r  = ei[e];
        int cc = ei[E + e];
        float d = expf(-ALPHA * (tmax - t[e]));
        if (c == 0) ebuf[e] = d;
        unsigned rr = (unsigned)(r - base);
        if (rr < CHUNK) atomicAdd(&ldsD[rr], d);
        unsigned cr = (unsigned)(cc - base);
        if (cr < CHUNK) atomicAdd(&ldsH[cr], 1);
    }
    __syncthreads();
    float*          pd = privD + ((size_t)c * SPLIT + b) * CHUNK;
    unsigned short* ph = privH + ((size_t)c * SPLIT + b) * CHUNK;
    for (int i = threadIdx.x; i < CHUNK; i += 1024) {
        pd[i] = ldsD[i];
        ph[i] = (unsigned short)ldsH[i];
    }
}

// ------ reduce SPLIT copies -> dinv (=rsqrt(deg)), hist; privH -> per-slice EXCL prefix ------
__global__ __launch_bounds__(256) void k_deghist_red(const float* __restrict__ privD,
                                                     unsigned short* __restrict__ privH,
                                                     float* __restrict__ dinv,
                                                     int* __restrict__ hist, int N) {
    int n = blockIdx.x * 256 + threadIdx.x;
    if (n >= N) return;
    int c = n >> CSHIFT;
    int i = n & (CHUNK - 1);
    const float*    pd = privD + ((size_t)c * SPLIT) * CHUNK + i;
    unsigned short* ph = privH + ((size_t)c * SPLIT) * CHUNK + i;
    float s = 0.f; int run = 0;
    #pragma unroll 8
    for (int b = 0; b < SPLIT; ++b) {
        s += pd[(size_t)b * CHUNK];
        int t = ph[(size_t)b * CHUNK];
        ph[(size_t)b * CHUNK] = (unsigned short)run;   // exclusive prefix within node bucket
        run += t;
    }
    dinv[n] = s > 0.f ? rsqrtf(s) : 0.f;
    hist[n] = run;
}

// ---------------- scan phase A: per-block sum of 1024-elem hist chunk ----------------
__global__ __launch_bounds__(256) void k_scan_a(const int* __restrict__ hist,
                                                int* __restrict__ bsum, int N) {
    __shared__ int sm[4];
    int base = blockIdx.x * SCAN_ELEMS + threadIdx.x * 4;
    int s = 0;
    if (base + 3 < N) {
        int4 v = *(const int4*)(hist + base);
        s = v.x + v.y + v.z + v.w;
    } else {
        for (int i = base; i < N && i < base + 4; ++i) s += hist[i];
    }
    #pragma unroll
    for (int off = 32; off > 0; off >>= 1) s += __shfl_down(s, off, 64);
    if ((threadIdx.x & 63) == 0) sm[threadIdx.x >> 6] = s;
    __syncthreads();
    if (threadIdx.x == 0) bsum[blockIdx.x] = sm[0] + sm[1] + sm[2] + sm[3];
}

// ------- scan phase B: 1 block scans <=1024 partials; writes rowptr[N]=total -------
__global__ __launch_bounds__(1024) void k_scan_b(const int* __restrict__ bsum,
                                                 int* __restrict__ boff,
                                                 int NB, int* __restrict__ rowptrN) {
    __shared__ int part[1024];
    int tid = threadIdx.x;
    int v = (tid < NB) ? bsum[tid] : 0;
    part[tid] = v;
    __syncthreads();
    for (int d = 1; d < 1024; d <<= 1) {
        int t = (tid >= d) ? part[tid - d] : 0;
        __syncthreads();
        part[tid] += t;
        __syncthreads();
    }
    if (tid < NB) boff[tid] = part[tid] - v;
    if (tid == 1023) *rowptrN = part[1023];
}

// ------- scan phase C: block-local scan + block offset -> rowptr ----------
__global__ __launch_bounds__(256) void k_scan_c(const int* __restrict__ hist,
                                                const int* __restrict__ boff,
                                                int* __restrict__ rowptr, int N) {
    __shared__ int part[256];
    int base = blockIdx.x * SCAN_ELEMS + threadIdx.x * 4;
    int vv[4] = {0, 0, 0, 0};
    if (base + 3 < N) {
        int4 v = *(const int4*)(hist + base);
        vv[0] = v.x; vv[1] = v.y; vv[2] = v.z; vv[3] = v.w;
    } else {
        for (int i = 0; i < 4; ++i) if (base + i < N) vv[i] = hist[base + i];
    }
    int s = vv[0] + vv[1] + vv[2] + vv[3];
    part[threadIdx.x] = s;
    __syncthreads();
    for (int d = 1; d < 256; d <<= 1) {
        int t = (threadIdx.x >= d) ? part[threadIdx.x - d] : 0;
        __syncthreads();
        part[threadIdx.x] += t;
        __syncthreads();
    }
    int run = boff[blockIdx.x] + part[threadIdx.x] - s;
    int pp[4];
    pp[0] = run;
    pp[1] = pp[0] + vv[0];
    pp[2] = pp[1] + vv[1];
    pp[3] = pp[2] + vv[2];
    if (base + 3 < N) {
        *(int4*)(rowptr + base) = make_int4(pp[0], pp[1], pp[2], pp[3]);
    } else {
        for (int i = 0; i < 4; ++i)
            if (base + i < N) rowptr[base + i] = pp[i];
    }
}

// ------- chunked CSR fill: packed int2 (src, w-bits), LDS cursor, no device atomics -------
__global__ __launch_bounds__(1024) void k_fill(const int* __restrict__ ei,
                                               const float* __restrict__ ebuf,
                                               const float* __restrict__ dinv,
                                               const int* __restrict__ rowptr,
                                               const unsigned short* __restrict__ privH,
                                               int2* __restrict__ pairs,
                                               int E, int N) {
    __shared__ int cur[CHUNK];      // 32 KiB
    int c = blockIdx.x / SPLIT;
    int b = blockIdx.x - c * SPLIT;
    int base = c * CHUNK;
    int lim = min(CHUNK, N - base);
    const unsigned short* ph = privH + ((size_t)c * SPLIT + b) * CHUNK;
    for (int i = threadIdx.x; i < lim; i += 1024)
        cur[i] = rowptr[base + i] + (int)ph[i];
    __syncthreads();
    long long e0 = (long long)E * b / SPLIT;
    long long e1 = (long long)E * (b + 1) / SPLIT;
    for (long long e = e0 + threadIdx.x; e < e1; e += 1024) {
        int cc = ei[E + e];
        unsigned cr = (unsigned)(cc - base);
        if (cr < (unsigned)lim) {
            int r = ei[e];
            int pos = atomicAdd(&cur[cr], 1);   // LDS atomic, block-exclusive
            float w = dinv[r] * ebuf[e] * dinv[cc];
            pairs[pos] = make_int2(r, __float_as_int(w));
        }
    }
}

// ------- dinv2[c] = rsqrt(1 + segment_sum(w))  (no atomics) -------
__global__ __launch_bounds__(256) void k_deg2(const int* __restrict__ rowptr,
                                              const int2* __restrict__ pairs,
                                              float* __restrict__ dinv2, int N) {
    int n = blockIdx.x * 256 + threadIdx.x;
    if (n >= N) return;
    int s = rowptr[n], e = rowptr[n + 1];
    float a = 1.f;
    for (int p = s; p < e; ++p) a += __int_as_float(pairs[p].y);
    dinv2[n] = rsqrtf(a);
}

// ======== g1 = bf16( dinv2 * (x @ W1) ) via MFMA 16x16x32 bf16 ========
__global__ __launch_bounds__(256) void k_mm1(const float* __restrict__ x,
                                             const unsigned short* __restrict__ W1t,
                                             const float* __restrict__ dinv2,
                                             unsigned short* __restrict__ gbuf, int N) {
    __shared__ __align__(16) unsigned short xb[64 * FIN];   // 16 KiB
    int tid  = threadIdx.x;
    int lane = tid & 63;
    int w    = tid >> 6;
    int lrow = lane & 15;
    int lk8  = lane >> 4;          // 0..3
    int tile0 = blockIdx.x * 64;
    if (tile0 >= N) return;
    int nrow = min(64, N - tile0);

    short8v breg[4][4];
    #pragma unroll
    for (int kk = 0; kk < 4; ++kk)
        #pragma unroll
        for (int ct = 0; ct < 4; ++ct)
            breg[kk][ct] = *(const short8v*)(W1t + (16 * ct + lrow) * FIN + kk * 32 + lk8 * 8);

    const float4* gx = (const float4*)(x + (size_t)tile0 * FIN);
    int nv = nrow * (FIN / 4);
    for (int i = tid; i < nv; i += 256) {
        float4 v = gx[i];
        int row = i >> 5;                      // FIN/4 = 32 float4 per row
        int byte = row * 256 + (i & 31) * 8;
        unsigned swz = (unsigned)(byte ^ ((row & 7) << 4));
        *(uint2*)((char*)xb + swz) = make_uint2(pack2(v.x, v.y), pack2(v.z, v.w));
    }
    __syncthreads();

    f32x4 acc[4];
    #pragma unroll
    for (int ct = 0; ct < 4; ++ct) acc[ct] = 0.f;
    int arow = 16 * w + lrow;
    #pragma unroll
    for (int kk = 0; kk < 4; ++kk) {
        int byte = arow * 256 + kk * 64 + lk8 * 16;
        unsigned swz = (unsigned)(byte ^ ((arow & 7) << 4));
        short8v a = *(const short8v*)((const char*)xb + swz);
        #pragma unroll
        for (int ct = 0; ct < 4; ++ct)
            acc[ct] = __builtin_amdgcn_mfma_f32_16x16x32_bf16(a, breg[kk][ct], acc[ct], 0, 0, 0);
    }
    #pragma unroll
    for (int i = 0; i < 4; ++i) {
        int grow = tile0 + 16 * w + lk8 * 4 + i;
        if (grow < N) {
            float sn = dinv2[grow];
            #pragma unroll
            for (int ct = 0; ct < 4; ++ct)
                gbuf[(size_t)grow * HD + 16 * ct + lrow] = f2bf(sn * acc[ct][i]);
        }
    }
}

// ======== g2 = bf16( dinv2 * (relu(agg+b1) @ W2) ) via MFMA, K=64 ========
__global__ __launch_bounds__(256) void k_mm2(const float* __restrict__ agg,
                                             const float* __restrict__ b1,
                                             const unsigned short* __restrict__ W2t,
                                             const float* __restrict__ dinv2,
                                             unsigned short* __restrict__ gbuf, int N) {
    __shared__ __align__(16) unsigned short xb[64 * HD];    // 8 KiB
    int tid  = threadIdx.x;
    int lane = tid & 63;
    int w    = tid >> 6;
    int lrow = lane & 15;
    int lk8  = lane >> 4;
    int tile0 = blockIdx.x * 64;
    if (tile0 >= N) return;
    int nrow = min(64, N - tile0);

    short8v breg[2][4];
    #pragma unroll
    for (int kk = 0; kk < 2; ++kk)
        #pragma unroll
        for (int ct = 0; ct < 4; ++ct)
            breg[kk][ct] = *(const short8v*)(W2t + (16 * ct + lrow) * HD + kk * 32 + lk8 * 8);

    const float4* gx = (const float4*)(agg + (size_t)tile0 * HD);
    const float4* bf4 = (const float4*)b1;
    int nv = nrow * (HD / 4);
    for (int i = tid; i < nv; i += 256) {
        float4 v = gx[i];
        float4 bb = bf4[i & 15];
        v.x = fmaxf(v.x + bb.x, 0.f);
        v.y = fmaxf(v.y + bb.y, 0.f);
        v.z = fmaxf(v.z + bb.z, 0.f);
        v.w = fmaxf(v.w + bb.w, 0.f);
        int row = i >> 4;                      // HD/4 = 16 float4 per row
        int byte = row * 128 + (i & 15) * 8;
        unsigned swz = (unsigned)(byte ^ ((row & 7) << 4));
        *(uint2*)((char*)xb + swz) = make_uint2(pack2(v.x, v.y), pack2(v.z, v.w));
    }
    __syncthreads();

    f32x4 acc[4];
    #pragma unroll
    for (int ct = 0; ct < 4; ++ct) acc[ct] = 0.f;
    int arow = 16 * w + lrow;
    #pragma unroll
    for (int kk = 0; kk < 2; ++kk) {
        int byte = arow * 128 + kk * 64 + lk8 * 16;
        unsigned swz = (unsigned)(byte ^ ((arow & 7) << 4));
        short8v a = *(const short8v*)((const char*)xb + swz);
        #pragma unroll
        for (int ct = 0; ct < 4; ++ct)
            acc[ct] = __builtin_amdgcn_mfma_f32_16x16x32_bf16(a, breg[kk][ct], acc[ct], 0, 0, 0);
    }
    #pragma unroll
    for (int i = 0; i < 4; ++i) {
        int grow = tile0 + 16 * w + lk8 * 4 + i;
        if (grow < N) {
            float sn = dinv2[grow];
            #pragma unroll
            for (int ct = 0; ct < 4; ++ct)
                gbuf[(size_t)grow * HD + 16 * ct + lrow] = f2bf(sn * acc[ct][i]);
        }
    }
}

// ------- CSR gather, 2 rows per gather instruction: lane-halves take even/odd edges;
//         each lane loads uint (2 bf16 features); cross-half combine via shfl_xor(32). -------
__global__ __launch_bounds__(256) void k_agg(const int* __restrict__ rowptr,
                                             const int2* __restrict__ pairs,
                                             const unsigned* __restrict__ g32,
                                             const float* __restrict__ dinv2,
                                             float* __restrict__ agg, int N) {
    int lane = threadIdx.x & 63;
    int node = (blockIdx.x * 256 + threadIdx.x) >> 6;
    if (node >= N) return;
    int half = lane >> 5;          // 0: even-indexed edges, 1: odd
    int fl   = lane & 31;          // feature-pair (features 2fl, 2fl+1)
    const unsigned* gl = g32 + fl;
    int s = rowptr[node];
    int e = rowptr[node + 1];
    float ax0 = 0.f, ay0 = 0.f, ax1 = 0.f, ay1 = 0.f;
    int p = s;
    for (; p + 8 <= e; p += 8) {               // 8 edges -> 4 gathers (2 rows each)
        int2 pr[8];
        #pragma unroll
        for (int j = 0; j < 8; ++j) pr[j] = pairs[p + j];
        unsigned v[4]; float w[4];
        #pragma unroll
        for (int j = 0; j < 4; ++j) {
            int2 mine = half ? pr[2 * j + 1] : pr[2 * j];
            w[j] = __int_as_float(mine.y);
            v[j] = gl[(size_t)mine.x * 32];
        }
        ax0 += w[0] * __uint_as_float(v[0] << 16);
        ay0 += w[0] * __uint_as_float(v[0] & 0xFFFF0000u);
        ax1 += w[1] * __uint_as_float(v[1] << 16);
        ay1 += w[1] * __uint_as_float(v[1] & 0xFFFF0000u);
        ax0 += w[2] * __uint_as_float(v[2] << 16);
        ay0 += w[2] * __uint_as_float(v[2] & 0xFFFF0000u);
        ax1 += w[3] * __uint_as_float(v[3] << 16);
        ay1 += w[3] * __uint_as_float(v[3] & 0xFFFF0000u);
    }
    if (p + 4 <= e) {                          // 4 edges -> 2 gathers
        int2 pr[4];
        #pragma unroll
        for (int j = 0; j < 4; ++j) pr[j] = pairs[p + j];
        unsigned v[2]; float w[2];
        #pragma unroll
        for (int j = 0; j < 2; ++j) {
            int2 mine = half ? pr[2 * j + 1] : pr[2 * j];
            w[j] = __int_as_float(mine.y);
            v[j] = gl[(size_t)mine.x * 32];
        }
        ax0 += w[0] * __uint_as_float(v[0] << 16);
        ay0 += w[0] * __uint_as_float(v[0] & 0xFFFF0000u);
        ax1 += w[1] * __uint_as_float(v[1] << 16);
        ay1 += w[1] * __uint_as_float(v[1] & 0xFFFF0000u);
        p += 4;
    }
    if (p + 2 <= e) {                          // 2 edges -> 1 gather
        int2 pe = pairs[p], po = pairs[p + 1];
        int2 mine = half ? po : pe;
        float w = __int_as_float(mine.y);
        unsigned v = gl[(size_t)mine.x * 32];
        ax0 += w * __uint_as_float(v << 16);
        ay0 += w * __uint_as_float(v & 0xFFFF0000u);
        p += 2;
    }
    if (p < e) {                               // 1 leftover edge: half 0 only
        int2 pr = pairs[p];
        if (half == 0) {
            float w = __int_as_float(pr.y);
            unsigned v = gl[(size_t)pr.x * 32];
            ax0 += w * __uint_as_float(v << 16);
            ay0 += w * __uint_as_float(v & 0xFFFF0000u);
        }
    }
    float ax = ax0 + ax1;
    float ay = ay0 + ay1;
    ax += __shfl_xor(ax, 32);                  // combine even/odd halves
    ay += __shfl_xor(ay, 32);
    if (half == 0) {
        unsigned sv = gl[(size_t)node * 32];   // self term g[node]
        float sn = dinv2[node];
        float2 o;
        o.x = sn * (ax + __uint_as_float(sv << 16));
        o.y = sn * (ay + __uint_as_float(sv & 0xFFFF0000u));
        *(float2*)(agg + (size_t)node * HD + fl * 2) = o;
    }
}

// ---------------- out = relu(agg + b2) @ Wout + bout ----------------
__global__ __launch_bounds__(256) void k_out(const float* __restrict__ agg,
                                             const float* __restrict__ b2,
                                             const float* __restrict__ Wout,
                                             const float* __restrict__ bout,
                                             float* __restrict__ out, int N) {
    __shared__ float Wl[HD * TD];
    __shared__ float bl[HD];
    __shared__ float bo[TD];
    for (int i = threadIdx.x; i < HD * TD; i += 256) Wl[i] = Wout[i];
    if (threadIdx.x < HD) bl[threadIdx.x] = b2[threadIdx.x];
    if (threadIdx.x < TD) bo[threadIdx.x] = bout[threadIdx.x];
    __syncthreads();
    int idx = blockIdx.x * 256 + threadIdx.x;
    if (idx >= N * TD) return;
    int n = idx / TD;
    int t = idx - n * TD;
    const float* a = agg + (size_t)n * HD;
    float acc = bo[t];
    #pragma unroll 8
    for (int k = 0; k < HD; ++k)
        acc += fmaxf(a[k] + bl[k], 0.f) * Wl[k * TD + t];
    out[idx] = acc;
}

extern "C" void kernel_launch(void* const* d_in, const int* in_sizes, int n_in,
                              void* d_out, int out_size, void* d_ws, size_t ws_size,
                              hipStream_t stream) {
    const float* x    = (const float*)d_in[0];
    const int*   ei   = (const int*)d_in[1];   // harness passes integers as int32
    const float* et   = (const float*)d_in[2];
    const float* W1   = (const float*)d_in[3];
    const float* b1   = (const float*)d_in[4];
    const float* W2   = (const float*)d_in[5];
    const float* b2   = (const float*)d_in[6];
    const float* Wout = (const float*)d_in[7];
    const float* bout = (const float*)d_in[8];
    float*       out  = (float*)d_out;

    int N = in_sizes[0] / FIN;
    int E = in_sizes[2];
    int NCHUNK = (N + CHUNK - 1) / CHUNK;          // 13 for N=100K
    int NB = (N + SCAN_ELEMS - 1) / SCAN_ELEMS;    // scan blocks (98)

    // --- workspace layout, 256B-aligned regions ---
    char*  base = (char*)d_ws;
    size_t ofs  = 0;
    auto alloc = [&](size_t bytes) -> char* {
        char* p = base + ofs;
        ofs = (ofs + bytes + 255) & ~(size_t)255;
        return p;
    };
    unsigned*       tmaxb = (unsigned*)alloc(64);
    unsigned short* W1t   = (unsigned short*)alloc((size_t)FIN * HD * 2);
    unsigned short* W2t   = (unsigned short*)alloc((size_t)HD * HD * 2);
    float*    ebuf   = (float*)alloc((size_t)E * 4);        // decay
    float*    dinv   = (float*)alloc((size_t)N * 4);
    float*    dinv2  = (float*)alloc((size_t)N * 4);
    int*      hist   = (int*)alloc((size_t)N * 4);
    int*      rowptr = (int*)alloc((size_t)(N + 1) * 4);
    int*      bsum   = (int*)alloc((size_t)1024 * 4);
    int*      boff   = (int*)alloc((size_t)1024 * 4);
    size_t privBytes = (size_t)NCHUNK * SPLIT * CHUNK * 4;  // 13.6 MB (privD f32)
    size_t pairBytes = (size_t)E * 8;                       // 12.8 MB
    // privD dead after k_deghist_red -> alias with pairs
    char*  privA = alloc(privBytes > pairBytes ? privBytes : pairBytes);
    float* privD = (float*)privA;
    int2*  pairs = (int2*)privA;
    unsigned short* privH = (unsigned short*)alloc(privBytes / 2);  // ushort, persists thru k_fill
    unsigned short* gbuf  = (unsigned short*)alloc((size_t)N * HD * 2);
    float* agg   = (float*)alloc((size_t)N * HD * 4);

    int bN  = (N + 255) / 256;
    int bT  = (N + 63) / 64;
    int bWN = (N * HD + 255) / 256;

    k_cvtW       <<<32,  256, 0, stream>>>(W1, W2, W1t, W2t, tmaxb);
    k_tmax       <<<256, 256, 0, stream>>>(et, tmaxb, E);
    k_deghist    <<<NCHUNK * SPLIT, 1024, 0, stream>>>(ei, et, tmaxb, ebuf, privD, privH, E, N);
    k_deghist_red<<<bN,  256, 0, stream>>>(privD, privH, dinv, hist, N);
    k_scan_a     <<<NB,  256, 0, stream>>>(hist, bsum, N);
    k_scan_b     <<<1,  1024, 0, stream>>>(bsum, boff, NB, rowptr + N);
    k_scan_c     <<<NB,  256, 0, stream>>>(hist, boff, rowptr, N);
    k_fill       <<<NCHUNK * SPLIT, 1024, 0, stream>>>(ei, ebuf, dinv, rowptr, privH, pairs, E, N);
    k_deg2       <<<bN,  256, 0, stream>>>(rowptr, pairs, dinv2, N);

    k_mm1        <<<bT,  256, 0, stream>>>(x, W1t, dinv2, gbuf, N);
    k_agg        <<<bWN, 256, 0, stream>>>(rowptr, pairs, (const unsigned*)gbuf, dinv2, agg, N);
    k_mm2        <<<bT,  256, 0, stream>>>(agg, b1, W2t, dinv2, gbuf, N);
    k_agg        <<<bWN, 256, 0, stream>>>(rowptr, pairs, (const unsigned*)gbuf, dinv2, agg, N);
    k_out        <<<(N * TD + 255) / 256, 256, 0, stream>>>(agg, b2, Wout, bout, out, N);
}

// Round 16
// 275.338 us; speedup vs baseline: 1.5500x; 1.5500x over previous
//
#include <hip/hip_runtime.h>

#define ALPHA 0.1f
#define FIN 128
#define HD 64
#define TD 10
#define SCAN_ELEMS 1024
#define CHUNK 16384           // nodes per LDS chunk (2^14)
#define CSHIFT 14
#define SPLIT 64              // edge-slices per chunk

typedef __attribute__((ext_vector_type(8))) short short8v;   // 8 bf16 (4 VGPRs)
typedef __attribute__((ext_vector_type(4))) float f32x4;

__device__ __forceinline__ unsigned short f2bf(float f) {    // RNE f32->bf16
    unsigned u = __float_as_uint(f);
    return (unsigned short)((u + 0x7FFFu + ((u >> 16) & 1u)) >> 16);
}
__device__ __forceinline__ unsigned pack2(float a, float b) {
    return (unsigned)f2bf(a) | ((unsigned)f2bf(b) << 16);
}
__device__ __forceinline__ float bf2f(unsigned short u) {
    return __uint_as_float((unsigned)u << 16);
}

// ------- convert W1/W2 -> transposed bf16 tables; also init tmax -------
__global__ __launch_bounds__(256) void k_cvtW(const float* __restrict__ W1,
                                              const float* __restrict__ W2,
                                              unsigned short* __restrict__ W1t,
                                              unsigned short* __restrict__ W2t,
                                              unsigned* tmaxb) {
    int t = blockIdx.x * 256 + threadIdx.x;
    if (t == 0) *tmaxb = 0u;
    if (t < FIN * HD) {                       // 8192
        int c = t >> 7, k = t & 127;
        W1t[t] = f2bf(W1[k * HD + c]);
    }
    if (t < HD * HD) {                        // 4096
        int c = t >> 6, k = t & 63;
        W2t[t] = f2bf(W2[k * HD + c]);
    }
}

// ---------------- max(edge_time): block-reduced, 1 atomic per block ----------------
__global__ __launch_bounds__(256) void k_tmax(const float* __restrict__ t, unsigned* tmaxb, int E) {
    __shared__ unsigned sm[4];
    unsigned m = 0u;
    for (int i = blockIdx.x * 256 + threadIdx.x; i < E; i += gridDim.x * 256)
        m = max(m, __float_as_uint(t[i]));
    #pragma unroll
    for (int off = 32; off > 0; off >>= 1)
        m = max(m, (unsigned)__shfl_down((int)m, off, 64));
    if ((threadIdx.x & 63) == 0) sm[threadIdx.x >> 6] = m;
    __syncthreads();
    if (threadIdx.x == 0) {
        m = max(max(sm[0], sm[1]), max(sm[2], sm[3]));
        atomicMax(tmaxb, m);
    }
}

// ------ chunked LDS-privatized deg (row, decay-weighted); reads only row idx + time ------
__global__ __launch_bounds__(1024) void k_deg(const int* __restrict__ ei,
                                              const float* __restrict__ t,
                                              const unsigned* __restrict__ tmaxb,
                                              float* __restrict__ ebuf,
                                              float* __restrict__ privD,
                                              int E, int N) {
    __shared__ float ldsD[CHUNK];   // 64 KiB
    int c = blockIdx.x / SPLIT;
    int b = blockIdx.x - c * SPLIT;
    int base = c * CHUNK;
    for (int i = threadIdx.x; i < CHUNK; i += 1024) ldsD[i] = 0.f;
    __syncthreads();
    float tmax = __uint_as_float(*tmaxb);
    long long e0 = (long long)E * b / SPLIT;
    long long e1 = (long long)E * (b + 1) / SPLIT;
    for (long long e = e0 + threadIdx.x; e < e1; e += 1024) {
        int r = ei[e];
        float d = expf(-ALPHA * (tmax - t[e]));
        if (c == 0) ebuf[e] = d;
        unsigned rr = (unsigned)(r - base);
        if (rr < CHUNK) atomicAdd(&ldsD[rr], d);
    }
    __syncthreads();
    float* pd = privD + ((size_t)c * SPLIT + b) * CHUNK;
    for (int i = threadIdx.x; i < CHUNK; i += 1024) pd[i] = ldsD[i];
}

// ------ chunked LDS-privatized hist (col counts); reads only col idx ------
__global__ __launch_bounds__(1024) void k_hist(const int* __restrict__ ei,
                                               unsigned short* __restrict__ privH,
                                               int E, int N) {
    __shared__ int ldsH[CHUNK];     // 64 KiB
    int c = blockIdx.x / SPLIT;
    int b = blockIdx.x - c * SPLIT;
    int base = c * CHUNK;
    for (int i = threadIdx.x; i < CHUNK; i += 1024) ldsH[i] = 0;
    __syncthreads();
    long long e0 = (long long)E * b / SPLIT;
    long long e1 = (long long)E * (b + 1) / SPLIT;
    for (long long e = e0 + threadIdx.x; e < e1; e += 1024) {
        int cc = ei[E + e];
        unsigned cr = (unsigned)(cc - base);
        if (cr < CHUNK) atomicAdd(&ldsH[cr], 1);
    }
    __syncthreads();
    unsigned short* ph = privH + ((size_t)c * SPLIT + b) * CHUNK;
    for (int i = threadIdx.x; i < CHUNK; i += 1024) ph[i] = (unsigned short)ldsH[i];
}

// ------ reduce SPLIT copies -> dinv (=rsqrt(deg)), hist; privH -> per-slice EXCL prefix ------
__global__ __launch_bounds__(256) void k_red(const float* __restrict__ privD,
                                             unsigned short* __restrict__ privH,
                                             float* __restrict__ dinv,
                                             int* __restrict__ hist, int N) {
    int n = blockIdx.x * 256 + threadIdx.x;
    if (n >= N) return;
    int c = n >> CSHIFT;
    int i = n & (CHUNK - 1);
    const float*    pd = privD + ((size_t)c * SPLIT) * CHUNK + i;
    unsigned short* ph = privH + ((size_t)c * SPLIT) * CHUNK + i;
    float s = 0.f; int run = 0;
    #pragma unroll 8
    for (int b = 0; b < SPLIT; ++b) {
        s += pd[(size_t)b * CHUNK];
        int t = ph[(size_t)b * CHUNK];
        ph[(size_t)b * CHUNK] = (unsigned short)run;   // exclusive prefix within node bucket
        run += t;
    }
    dinv[n] = s > 0.f ? rsqrtf(s) : 0.f;
    hist[n] = run;
}

// ---------------- scan phase A: per-block sum of 1024-elem hist chunk ----------------
__global__ __launch_bounds__(256) void k_scan_a(const int* __restrict__ hist,
                                                int* __restrict__ bsum, int N) {
    __shared__ int sm[4];
    int base = blockIdx.x * SCAN_ELEMS + threadIdx.x * 4;
    int s = 0;
    if (base + 3 < N) {
        int4 v = *(const int4*)(hist + base);
        s = v.x + v.y + v.z + v.w;
    } else {
        for (int i = base; i < N && i < base + 4; ++i) s += hist[i];
    }
    #pragma unroll
    for (int off = 32; off > 0; off >>= 1) s += __shfl_down(s, off, 64);
    if ((threadIdx.x & 63) == 0) sm[threadIdx.x >> 6] = s;
    __syncthreads();
    if (threadIdx.x == 0) bsum[blockIdx.x] = sm[0] + sm[1] + sm[2] + sm[3];
}

// ------- scan phase B: 1 block scans <=1024 partials; writes rowptr[N]=total -------
__global__ __launch_bounds__(1024) void k_scan_b(const int* __restrict__ bsum,
                                                 int* __restrict__ boff,
                                                 int NB, int* __restrict__ rowptrN) {
    __shared__ int part[1024];
    int tid = threadIdx.x;
    int v = (tid < NB) ? bsum[tid] : 0;
    part[tid] = v;
    __syncthreads();
    for (int d = 1; d < 1024; d <<= 1) {
        int t = (tid >= d) ? part[tid - d] : 0;
        __syncthreads();
        part[tid] += t;
        __syncthreads();
    }
    if (tid < NB) boff[tid] = part[tid] - v;
    if (tid == 1023) *rowptrN = part[1023];
}

// ------- scan phase C: block-local scan + block offset -> rowptr ----------
__global__ __launch_bounds__(256) void k_scan_c(const int* __restrict__ hist,
                                                const int* __restrict__ boff,
                                                int* __restrict__ rowptr, int N) {
    __shared__ int part[256];
    int base = blockIdx.x * SCAN_ELEMS + threadIdx.x * 4;
    int vv[4] = {0, 0, 0, 0};
    if (base + 3 < N) {
        int4 v = *(const int4*)(hist + base);
        vv[0] = v.x; vv[1] = v.y; vv[2] = v.z; vv[3] = v.w;
    } else {
        for (int i = 0; i < 4; ++i) if (base + i < N) vv[i] = hist[base + i];
    }
    int s = vv[0] + vv[1] + vv[2] + vv[3];
    part[threadIdx.x] = s;
    __syncthreads();
    for (int d = 1; d < 256; d <<= 1) {
        int t = (threadIdx.x >= d) ? part[threadIdx.x - d] : 0;
        __syncthreads();
        part[threadIdx.x] += t;
        __syncthreads();
    }
    int run = boff[blockIdx.x] + part[threadIdx.x] - s;
    int pp[4];
    pp[0] = run;
    pp[1] = pp[0] + vv[0];
    pp[2] = pp[1] + vv[1];
    pp[3] = pp[2] + vv[2];
    if (base + 3 < N) {
        *(int4*)(rowptr + base) = make_int4(pp[0], pp[1], pp[2], pp[3]);
    } else {
        for (int i = 0; i < 4; ++i)
            if (base + i < N) rowptr[base + i] = pp[i];
    }
}

// ------- chunked CSR fill: packed int2 (src, w-bits), LDS cursor, no device atomics -------
__global__ __launch_bounds__(1024) void k_fill(const int* __restrict__ ei,
                                               const float* __restrict__ ebuf,
                                               const float* __restrict__ dinv,
                                               const int* __restrict__ rowptr,
                                               const unsigned short* __restrict__ privH,
                                               int2* __restrict__ pairs,
                                               int E, int N) {
    __shared__ int cur[CHUNK];      // 64 KiB
    int c = blockIdx.x / SPLIT;
    int b = blockIdx.x - c * SPLIT;
    int base = c * CHUNK;
    int lim = min(CHUNK, N - base);
    const unsigned short* ph = privH + ((size_t)c * SPLIT + b) * CHUNK;
    for (int i = threadIdx.x; i < lim; i += 1024)
        cur[i] = rowptr[base + i] + (int)ph[i];
    __syncthreads();
    long long e0 = (long long)E * b / SPLIT;
    long long e1 = (long long)E * (b + 1) / SPLIT;
    for (long long e = e0 + threadIdx.x; e < e1; e += 1024) {
        int cc = ei[E + e];
        unsigned cr = (unsigned)(cc - base);
        if (cr < (unsigned)lim) {
            int r = ei[e];
            int pos = atomicAdd(&cur[cr], 1);   // LDS atomic, block-exclusive
            float w = dinv[r] * ebuf[e] * dinv[cc];
            pairs[pos] = make_int2(r, __float_as_int(w));
        }
    }
}

// ------- dinv2[c] = rsqrt(1 + segment_sum(w))  (no atomics) -------
__global__ __launch_bounds__(256) void k_deg2(const int* __restrict__ rowptr,
                                              const int2* __restrict__ pairs,
                                              float* __restrict__ dinv2, int N) {
    int n = blockIdx.x * 256 + threadIdx.x;
    if (n >= N) return;
    int s = rowptr[n], e = rowptr[n + 1];
    float a = 1.f;
    for (int p = s; p < e; ++p) a += __int_as_float(pairs[p].y);
    dinv2[n] = rsqrtf(a);
}

// ======== g1 = bf16( dinv2 * (x @ W1) ) via MFMA 16x16x32 bf16 ========
__global__ __launch_bounds__(256) void k_mm1(const float* __restrict__ x,
                                             const unsigned short* __restrict__ W1t,
                                             const float* __restrict__ dinv2,
                                             unsigned short* __restrict__ gbuf, int N) {
    __shared__ __align__(16) unsigned short xb[64 * FIN];   // 16 KiB
    int tid  = threadIdx.x;
    int lane = tid & 63;
    int w    = tid >> 6;
    int lrow = lane & 15;
    int lk8  = lane >> 4;          // 0..3
    int tile0 = blockIdx.x * 64;
    if (tile0 >= N) return;
    int nrow = min(64, N - tile0);

    short8v breg[4][4];
    #pragma unroll
    for (int kk = 0; kk < 4; ++kk)
        #pragma unroll
        for (int ct = 0; ct < 4; ++ct)
            breg[kk][ct] = *(const short8v*)(W1t + (16 * ct + lrow) * FIN + kk * 32 + lk8 * 8);

    const float4* gx = (const float4*)(x + (size_t)tile0 * FIN);
    int nv = nrow * (FIN / 4);
    for (int i = tid; i < nv; i += 256) {
        float4 v = gx[i];
        int row = i >> 5;                      // FIN/4 = 32 float4 per row
        int byte = row * 256 + (i & 31) * 8;
        unsigned swz = (unsigned)(byte ^ ((row & 7) << 4));
        *(uint2*)((char*)xb + swz) = make_uint2(pack2(v.x, v.y), pack2(v.z, v.w));
    }
    __syncthreads();

    f32x4 acc[4];
    #pragma unroll
    for (int ct = 0; ct < 4; ++ct) acc[ct] = 0.f;
    int arow = 16 * w + lrow;
    #pragma unroll
    for (int kk = 0; kk < 4; ++kk) {
        int byte = arow * 256 + kk * 64 + lk8 * 16;
        unsigned swz = (unsigned)(byte ^ ((arow & 7) << 4));
        short8v a = *(const short8v*)((const char*)xb + swz);
        #pragma unroll
        for (int ct = 0; ct < 4; ++ct)
            acc[ct] = __builtin_amdgcn_mfma_f32_16x16x32_bf16(a, breg[kk][ct], acc[ct], 0, 0, 0);
    }
    #pragma unroll
    for (int i = 0; i < 4; ++i) {
        int grow = tile0 + 16 * w + lk8 * 4 + i;
        if (grow < N) {
            float sn = dinv2[grow];
            #pragma unroll
            for (int ct = 0; ct < 4; ++ct)
                gbuf[(size_t)grow * HD + 16 * ct + lrow] = f2bf(sn * acc[ct][i]);
        }
    }
}

// ======== g2 = bf16( dinv2 * (relu(agg+b1) @ W2) ) via MFMA, K=64 ========
__global__ __launch_bounds__(256) void k_mm2(const float* __restrict__ agg,
                                             const float* __restrict__ b1,
                                             const unsigned short* __restrict__ W2t,
                                             const float* __restrict__ dinv2,
                                             unsigned short* __restrict__ gbuf, int N) {
    __shared__ __align__(16) unsigned short xb[64 * HD];    // 8 KiB
    int tid  = threadIdx.x;
    int lane = tid & 63;
    int w    = tid >> 6;
    int lrow = lane & 15;
    int lk8  = lane >> 4;
    int tile0 = blockIdx.x * 64;
    if (tile0 >= N) return;
    int nrow = min(64, N - tile0);

    short8v breg[2][4];
    #pragma unroll
    for (int kk = 0; kk < 2; ++kk)
        #pragma unroll
        for (int ct = 0; ct < 4; ++ct)
            breg[kk][ct] = *(const short8v*)(W2t + (16 * ct + lrow) * HD + kk * 32 + lk8 * 8);

    const float4* gx = (const float4*)(agg + (size_t)tile0 * HD);
    const float4* bf4 = (const float4*)b1;
    int nv = nrow * (HD / 4);
    for (int i = tid; i < nv; i += 256) {
        float4 v = gx[i];
        float4 bb = bf4[i & 15];
        v.x = fmaxf(v.x + bb.x, 0.f);
        v.y = fmaxf(v.y + bb.y, 0.f);
        v.z = fmaxf(v.z + bb.z, 0.f);
        v.w = fmaxf(v.w + bb.w, 0.f);
        int row = i >> 4;                      // HD/4 = 16 float4 per row
        int byte = row * 128 + (i & 15) * 8;
        unsigned swz = (unsigned)(byte ^ ((row & 7) << 4));
        *(uint2*)((char*)xb + swz) = make_uint2(pack2(v.x, v.y), pack2(v.z, v.w));
    }
    __syncthreads();

    f32x4 acc[4];
    #pragma unroll
    for (int ct = 0; ct < 4; ++ct) acc[ct] = 0.f;
    int arow = 16 * w + lrow;
    #pragma unroll
    for (int kk = 0; kk < 2; ++kk) {
        int byte = arow * 128 + kk * 64 + lk8 * 16;
        unsigned swz = (unsigned)(byte ^ ((arow & 7) << 4));
        short8v a = *(const short8v*)((const char*)xb + swz);
        #pragma unroll
        for (int ct = 0; ct < 4; ++ct)
            acc[ct] = __builtin_amdgcn_mfma_f32_16x16x32_bf16(a, breg[kk][ct], acc[ct], 0, 0, 0);
    }
    #pragma unroll
    for (int i = 0; i < 4; ++i) {
        int grow = tile0 + 16 * w + lk8 * 4 + i;
        if (grow < N) {
            float sn = dinv2[grow];
            #pragma unroll
            for (int ct = 0; ct < 4; ++ct)
                gbuf[(size_t)grow * HD + 16 * ct + lrow] = f2bf(sn * acc[ct][i]);
        }
    }
}

// ------- CSR gather, software-pipelined batch-8 (round-13 verbatim: measured 59.3 us) -------
__global__ __launch_bounds__(256) void k_agg(const int* __restrict__ rowptr,
                                             const int2* __restrict__ pairs,
                                             const unsigned short* __restrict__ g,
                                             const float* __restrict__ dinv2,
                                             float* __restrict__ agg, int N) {
    int lane = threadIdx.x & 63;
    int node = (blockIdx.x * 256 + threadIdx.x) >> 6;
    if (node >= N) return;
    int s = rowptr[node];
    int e = rowptr[node + 1];
    float a0 = bf2f(g[(size_t)node * HD + lane]);
    float a1 = 0.f, a2 = 0.f, a3 = 0.f;
    int p = s;
    int nb = (e - s) >> 3;                       // full 8-batches
    if (nb > 0) {
        int2 prA[8], prB[8];
        #pragma unroll
        for (int j = 0; j < 8; ++j) prA[j] = pairs[p + j];       // prologue
        for (int b = 0; b < nb; ++b) {
            if (b + 1 < nb) {
                #pragma unroll
                for (int j = 0; j < 8; ++j) prB[j] = pairs[p + 8 + j];   // prefetch next
            }
            float v[8];
            #pragma unroll
            for (int j = 0; j < 8; ++j)                          // 8 indep gathers
                v[j] = bf2f(g[(size_t)prA[j].x * HD + lane]);
            a0 += __int_as_float(prA[0].y) * v[0] + __int_as_float(prA[4].y) * v[4];
            a1 += __int_as_float(prA[1].y) * v[1] + __int_as_float(prA[5].y) * v[5];
            a2 += __int_as_float(prA[2].y) * v[2] + __int_as_float(prA[6].y) * v[6];
            a3 += __int_as_float(prA[3].y) * v[3] + __int_as_float(prA[7].y) * v[7];
            #pragma unroll
            for (int j = 0; j < 8; ++j) prA[j] = prB[j];         // rotate buffers
            p += 8;
        }
    }
    if (p + 4 <= e) {
        int2 pr[4];
        #pragma unroll
        for (int j = 0; j < 4; ++j) pr[j] = pairs[p + j];
        float v[4];
        #pragma unroll
        for (int j = 0; j < 4; ++j)
            v[j] = bf2f(g[(size_t)pr[j].x * HD + lane]);
        a0 += __int_as_float(pr[0].y) * v[0];
        a1 += __int_as_float(pr[1].y) * v[1];
        a2 += __int_as_float(pr[2].y) * v[2];
        a3 += __int_as_float(pr[3].y) * v[3];
        p += 4;
    }
    for (; p < e; ++p) {
        int2 pr = pairs[p];
        a0 += __int_as_float(pr.y) * bf2f(g[(size_t)pr.x * HD + lane]);
    }
    agg[(size_t)node * HD + lane] = dinv2[node] * ((a0 + a1) + (a2 + a3));
}

// ---------------- out = relu(agg + b2) @ Wout + bout ----------------
__global__ __launch_bounds__(256) void k_out(const float* __restrict__ agg,
                                             const float* __restrict__ b2,
                                             const float* __restrict__ Wout,
                                             const float* __restrict__ bout,
                                             float* __restrict__ out, int N) {
    __shared__ float Wl[HD * TD];
    __shared__ float bl[HD];
    __shared__ float bo[TD];
    for (int i = threadIdx.x; i < HD * TD; i += 256) Wl[i] = Wout[i];
    if (threadIdx.x < HD) bl[threadIdx.x] = b2[threadIdx.x];
    if (threadIdx.x < TD) bo[threadIdx.x] = bout[threadIdx.x];
    __syncthreads();
    int idx = blockIdx.x * 256 + threadIdx.x;
    if (idx >= N * TD) return;
    int n = idx / TD;
    int t = idx - n * TD;
    const float* a = agg + (size_t)n * HD;
    float acc = bo[t];
    #pragma unroll 8
    for (int k = 0; k < HD; ++k)
        acc += fmaxf(a[k] + bl[k], 0.f) * Wl[k * TD + t];
    out[idx] = acc;
}

extern "C" void kernel_launch(void* const* d_in, const int* in_sizes, int n_in,
                              void* d_out, int out_size, void* d_ws, size_t ws_size,
                              hipStream_t stream) {
    const float* x    = (const float*)d_in[0];
    const int*   ei   = (const int*)d_in[1];   // harness passes integers as int32
    const float* et   = (const float*)d_in[2];
    const float* W1   = (const float*)d_in[3];
    const float* b1   = (const float*)d_in[4];
    const float* W2   = (const float*)d_in[5];
    const float* b2   = (const float*)d_in[6];
    const float* Wout = (const float*)d_in[7];
    const float* bout = (const float*)d_in[8];
    float*       out  = (float*)d_out;

    int N = in_sizes[0] / FIN;
    int E = in_sizes[2];
    int NCHUNK = (N + CHUNK - 1) / CHUNK;          // 7 for N=100K
    int NB = (N + SCAN_ELEMS - 1) / SCAN_ELEMS;    // scan blocks (98)

    // --- workspace layout, 256B-aligned regions, with lifetime aliasing ---
    char*  base = (char*)d_ws;
    size_t ofs  = 0;
    auto alloc = [&](size_t bytes) -> char* {
        char* p = base + ofs;
        ofs = (ofs + bytes + 255) & ~(size_t)255;
        return p;
    };
    unsigned*       tmaxb = (unsigned*)alloc(64);
    unsigned short* W1t   = (unsigned short*)alloc((size_t)FIN * HD * 2);
    unsigned short* W2t   = (unsigned short*)alloc((size_t)HD * HD * 2);
    float*    ebuf   = (float*)alloc((size_t)E * 4);        // decay
    float*    dinv   = (float*)alloc((size_t)N * 4);
    float*    dinv2  = (float*)alloc((size_t)N * 4);
    int*      hist   = (int*)alloc((size_t)N * 4);
    int*      rowptr = (int*)alloc((size_t)(N + 1) * 4);
    int*      bsum   = (int*)alloc((size_t)1024 * 4);
    int*      boff   = (int*)alloc((size_t)1024 * 4);

    size_t privDBytes = (size_t)NCHUNK * SPLIT * CHUNK * 4;          // 29.4 MB
    size_t pairBytes  = (((size_t)E * 8) + 255) & ~(size_t)255;      // 12.8 MB
    size_t gbufBytes  = (size_t)N * HD * 2;                          // 12.8 MB
    size_t regionX = privDBytes > pairBytes + gbufBytes ? privDBytes : pairBytes + gbufBytes;
    char* X = alloc(regionX);
    float*          privD = (float*)X;                 // live k_deg -> k_red
    int2*           pairs = (int2*)X;                  // live k_fill -> end
    unsigned short* gbuf  = (unsigned short*)(X + pairBytes);  // live k_mm1 -> end

    size_t privHBytes = (size_t)NCHUNK * SPLIT * CHUNK * 2;          // 14.7 MB
    size_t aggBytes   = (size_t)N * HD * 4;                          // 25.6 MB
    size_t regionY = privHBytes > aggBytes ? privHBytes : aggBytes;
    char* Y = alloc(regionY);
    unsigned short* privH = (unsigned short*)Y;        // live k_hist -> k_fill
    float*          agg   = (float*)Y;                 // live k_agg -> end

    int bN  = (N + 255) / 256;
    int bT  = (N + 63) / 64;
    int bWN = (N * HD + 255) / 256;
    int bCS = NCHUNK * SPLIT;                          // 448 chunked blocks

    k_cvtW  <<<32,  256, 0, stream>>>(W1, W2, W1t, W2t, tmaxb);
    k_tmax  <<<256, 256, 0, stream>>>(et, tmaxb, E);
    k_deg   <<<bCS, 1024, 0, stream>>>(ei, et, tmaxb, ebuf, privD, E, N);
    k_hist  <<<bCS, 1024, 0, stream>>>(ei, privH, E, N);
    k_red   <<<bN,  256, 0, stream>>>(privD, privH, dinv, hist, N);
    k_scan_a<<<NB,  256, 0, stream>>>(hist, bsum, N);
    k_scan_b<<<1,  1024, 0, stream>>>(bsum, boff, NB, rowptr + N);
    k_scan_c<<<NB,  256, 0, stream>>>(hist, boff, rowptr, N);
    k_fill  <<<bCS, 1024, 0, stream>>>(ei, ebuf, dinv, rowptr, privH, pairs, E, N);
    k_deg2  <<<bN,  256, 0, stream>>>(rowptr, pairs, dinv2, N);

    k_mm1   <<<bT,  256, 0, stream>>>(x, W1t, dinv2, gbuf, N);
    k_agg   <<<bWN, 256, 0, stream>>>(rowptr, pairs, gbuf, dinv2, agg, N);
    k_mm2   <<<bT,  256, 0, stream>>>(agg, b1, W2t, dinv2, gbuf, N);
    k_agg   <<<bWN, 256, 0, stream>>>(rowptr, pairs, gbuf, dinv2, agg, N);
    k_out   <<<(N * TD + 255) / 256, 256, 0, stream>>>(agg, b2, Wout, bout, out, N);
}

// Round 17
// 272.607 us; speedup vs baseline: 1.5655x; 1.0100x over previous
//
#include <hip/hip_runtime.h>

#define ALPHA 0.1f
#define FIN 128
#define HD 64
#define TD 10
#define SCAN_ELEMS 1024
#define CHUNK 16384           // fill/privH chunk (2^14)
#define CSHIFT 14
#define CHUNK_D 32768         // deg chunk (2^15), 128 KiB LDS
#define CSHIFT_D 15
#define SPLIT 64              // edge-slices per chunk (shared by hist & fill)

typedef __attribute__((ext_vector_type(8))) short short8v;   // 8 bf16 (4 VGPRs)
typedef __attribute__((ext_vector_type(4))) float f32x4;

__device__ __forceinline__ unsigned short f2bf(float f) {    // RNE f32->bf16
    unsigned u = __float_as_uint(f);
    return (unsigned short)((u + 0x7FFFu + ((u >> 16) & 1u)) >> 16);
}
__device__ __forceinline__ unsigned pack2(float a, float b) {
    return (unsigned)f2bf(a) | ((unsigned)f2bf(b) << 16);
}
__device__ __forceinline__ float bf2f(unsigned short u) {
    return __uint_as_float((unsigned)u << 16);
}

// ------- convert W1/W2 -> transposed bf16 tables; also init tmax -------
__global__ __launch_bounds__(256) void k_cvtW(const float* __restrict__ W1,
                                              const float* __restrict__ W2,
                                              unsigned short* __restrict__ W1t,
                                              unsigned short* __restrict__ W2t,
                                              unsigned* tmaxb) {
    int t = blockIdx.x * 256 + threadIdx.x;
    if (t == 0) *tmaxb = 0u;
    if (t < FIN * HD) {                       // 8192
        int c = t >> 7, k = t & 127;
        W1t[t] = f2bf(W1[k * HD + c]);
    }
    if (t < HD * HD) {                        // 4096
        int c = t >> 6, k = t & 63;
        W2t[t] = f2bf(W2[k * HD + c]);
    }
}

// ---------------- max(edge_time): block-reduced, 1 atomic per block ----------------
__global__ __launch_bounds__(256) void k_tmax(const float* __restrict__ t, unsigned* tmaxb, int E) {
    __shared__ unsigned sm[4];
    unsigned m = 0u;
    for (int i = blockIdx.x * 256 + threadIdx.x; i < E; i += gridDim.x * 256)
        m = max(m, __float_as_uint(t[i]));
    #pragma unroll
    for (int off = 32; off > 0; off >>= 1)
        m = max(m, (unsigned)__shfl_down((int)m, off, 64));
    if ((threadIdx.x & 63) == 0) sm[threadIdx.x >> 6] = m;
    __syncthreads();
    if (threadIdx.x == 0) {
        m = max(max(sm[0], sm[1]), max(sm[2], sm[3]));
        atomicMax(tmaxb, m);
    }
}

// ------ chunked LDS-privatized deg (row, decay-weighted); 128 KiB LDS, 4 passes ------
__global__ __launch_bounds__(1024) void k_deg(const int* __restrict__ ei,
                                              const float* __restrict__ t,
                                              const unsigned* __restrict__ tmaxb,
                                              float* __restrict__ ebuf,
                                              float* __restrict__ privD,
                                              int E, int N) {
    __shared__ float ldsD[CHUNK_D];   // 128 KiB
    int c = blockIdx.x / SPLIT;
    int b = blockIdx.x - c * SPLIT;
    int base = c * CHUNK_D;
    for (int i = threadIdx.x; i < CHUNK_D; i += 1024) ldsD[i] = 0.f;
    __syncthreads();
    float tmax = __uint_as_float(*tmaxb);
    long long e0 = (long long)E * b / SPLIT;
    long long e1 = (long long)E * (b + 1) / SPLIT;
    for (long long e = e0 + threadIdx.x; e < e1; e += 1024) {
        int r = ei[e];
        float d = expf(-ALPHA * (tmax - t[e]));
        if (c == 0) ebuf[e] = d;
        unsigned rr = (unsigned)(r - base);
        if (rr < CHUNK_D) atomicAdd(&ldsD[rr], d);
    }
    __syncthreads();
    float* pd = privD + ((size_t)c * SPLIT + b) * CHUNK_D;
    for (int i = threadIdx.x; i < CHUNK_D; i += 1024) pd[i] = ldsD[i];
}

// ------ chunked hist (col counts): packed 2 x u16 per int, 32768 nodes / 64 KiB, 4 passes.
//        Dumps TWO 16384-node privH segments so downstream layout is unchanged. ------
__global__ __launch_bounds__(1024) void k_hist(const int* __restrict__ ei,
                                               unsigned short* __restrict__ privH,
                                               int E, int N) {
    __shared__ unsigned ldsP[CHUNK_D / 2];   // 64 KiB, node i in bits 16*(i&1)
    int c2 = blockIdx.x / SPLIT;
    int b  = blockIdx.x - c2 * SPLIT;
    int base = c2 * CHUNK_D;
    for (int i = threadIdx.x; i < CHUNK_D / 2; i += 1024) ldsP[i] = 0u;
    __syncthreads();
    long long e0 = (long long)E * b / SPLIT;
    long long e1 = (long long)E * (b + 1) / SPLIT;
    for (long long e = e0 + threadIdx.x; e < e1; e += 1024) {
        int cc = ei[E + e];
        unsigned cr = (unsigned)(cc - base);
        if (cr < CHUNK_D) atomicAdd(&ldsP[cr >> 1], 1u << ((cr & 1) * 16));
    }
    __syncthreads();
    #pragma unroll
    for (int s = 0; s < 2; ++s) {
        int c = 2 * c2 + s;                   // fill-chunk index
        unsigned short* ph = privH + ((size_t)c * SPLIT + b) * CHUNK;
        for (int i = threadIdx.x; i < CHUNK; i += 1024) {
            int gi = s * CHUNK + i;
            ph[i] = (unsigned short)((ldsP[gi >> 1] >> ((gi & 1) * 16)) & 0xFFFFu);
        }
    }
}

// ------ reduce SPLIT copies -> dinv (=rsqrt(deg)), hist; privH -> per-slice EXCL prefix ------
__global__ __launch_bounds__(256) void k_red(const float* __restrict__ privD,
                                             unsigned short* __restrict__ privH,
                                             float* __restrict__ dinv,
                                             int* __restrict__ hist, int N) {
    int n = blockIdx.x * 256 + threadIdx.x;
    if (n >= N) return;
    int cD = n >> CSHIFT_D;
    int iD = n & (CHUNK_D - 1);
    int cH = n >> CSHIFT;
    int iH = n & (CHUNK - 1);
    const float*    pd = privD + ((size_t)cD * SPLIT) * CHUNK_D + iD;
    unsigned short* ph = privH + ((size_t)cH * SPLIT) * CHUNK + iH;
    float s = 0.f; int run = 0;
    #pragma unroll 8
    for (int b = 0; b < SPLIT; ++b) {
        s += pd[(size_t)b * CHUNK_D];
        int t = ph[(size_t)b * CHUNK];
        ph[(size_t)b * CHUNK] = (unsigned short)run;   // exclusive prefix within node bucket
        run += t;
    }
    dinv[n] = s > 0.f ? rsqrtf(s) : 0.f;
    hist[n] = run;
}

// ---------------- scan phase A: per-block sum of 1024-elem hist chunk ----------------
__global__ __launch_bounds__(256) void k_scan_a(const int* __restrict__ hist,
                                                int* __restrict__ bsum, int N) {
    __shared__ int sm[4];
    int base = blockIdx.x * SCAN_ELEMS + threadIdx.x * 4;
    int s = 0;
    if (base + 3 < N) {
        int4 v = *(const int4*)(hist + base);
        s = v.x + v.y + v.z + v.w;
    } else {
        for (int i = base; i < N && i < base + 4; ++i) s += hist[i];
    }
    #pragma unroll
    for (int off = 32; off > 0; off >>= 1) s += __shfl_down(s, off, 64);
    if ((threadIdx.x & 63) == 0) sm[threadIdx.x >> 6] = s;
    __syncthreads();
    if (threadIdx.x == 0) bsum[blockIdx.x] = sm[0] + sm[1] + sm[2] + sm[3];
}

// ------- scan phase B: 1 block scans <=1024 partials; writes rowptr[N]=total -------
__global__ __launch_bounds__(1024) void k_scan_b(const int* __restrict__ bsum,
                                                 int* __restrict__ boff,
                                                 int NB, int* __restrict__ rowptrN) {
    __shared__ int part[1024];
    int tid = threadIdx.x;
    int v = (tid < NB) ? bsum[tid] : 0;
    part[tid] = v;
    __syncthreads();
    for (int d = 1; d < 1024; d <<= 1) {
        int t = (tid >= d) ? part[tid - d] : 0;
        __syncthreads();
        part[tid] += t;
        __syncthreads();
    }
    if (tid < NB) boff[tid] = part[tid] - v;
    if (tid == 1023) *rowptrN = part[1023];
}

// ------- scan phase C: block-local scan + block offset -> rowptr ----------
__global__ __launch_bounds__(256) void k_scan_c(const int* __restrict__ hist,
                                                const int* __restrict__ boff,
                                                int* __restrict__ rowptr, int N) {
    __shared__ int part[256];
    int base = blockIdx.x * SCAN_ELEMS + threadIdx.x * 4;
    int vv[4] = {0, 0, 0, 0};
    if (base + 3 < N) {
        int4 v = *(const int4*)(hist + base);
        vv[0] = v.x; vv[1] = v.y; vv[2] = v.z; vv[3] = v.w;
    } else {
        for (int i = 0; i < 4; ++i) if (base + i < N) vv[i] = hist[base + i];
    }
    int s = vv[0] + vv[1] + vv[2] + vv[3];
    part[threadIdx.x] = s;
    __syncthreads();
    for (int d = 1; d < 256; d <<= 1) {
        int t = (threadIdx.x >= d) ? part[threadIdx.x - d] : 0;
        __syncthreads();
        part[threadIdx.x] += t;
        __syncthreads();
    }
    int run = boff[blockIdx.x] + part[threadIdx.x] - s;
    int pp[4];
    pp[0] = run;
    pp[1] = pp[0] + vv[0];
    pp[2] = pp[1] + vv[1];
    pp[3] = pp[2] + vv[2];
    if (base + 3 < N) {
        *(int4*)(rowptr + base) = make_int4(pp[0], pp[1], pp[2], pp[3]);
    } else {
        for (int i = 0; i < 4; ++i)
            if (base + i < N) rowptr[base + i] = pp[i];
    }
}

// ------- chunked CSR fill: packed int2 (src, w-bits), LDS cursor, no device atomics -------
__global__ __launch_bounds__(1024) void k_fill(const int* __restrict__ ei,
                                               const float* __restrict__ ebuf,
                                               const float* __restrict__ dinv,
                                               const int* __restrict__ rowptr,
                                               const unsigned short* __restrict__ privH,
                                               int2* __restrict__ pairs,
                                               int E, int N) {
    __shared__ int cur[CHUNK];      // 64 KiB
    int c = blockIdx.x / SPLIT;
    int b = blockIdx.x - c * SPLIT;
    int base = c * CHUNK;
    int lim = min(CHUNK, N - base);
    const unsigned short* ph = privH + ((size_t)c * SPLIT + b) * CHUNK;
    for (int i = threadIdx.x; i < lim; i += 1024)
        cur[i] = rowptr[base + i] + (int)ph[i];
    __syncthreads();
    long long e0 = (long long)E * b / SPLIT;
    long long e1 = (long long)E * (b + 1) / SPLIT;
    for (long long e = e0 + threadIdx.x; e < e1; e += 1024) {
        int cc = ei[E + e];
        unsigned cr = (unsigned)(cc - base);
        if (cr < (unsigned)lim) {
            int r = ei[e];
            int pos = atomicAdd(&cur[cr], 1);   // LDS atomic, block-exclusive
            float w = dinv[r] * ebuf[e] * dinv[cc];
            pairs[pos] = make_int2(r, __float_as_int(w));
        }
    }
}

// ------- dinv2[c] = rsqrt(1 + segment_sum(w))  (no atomics) -------
__global__ __launch_bounds__(256) void k_deg2(const int* __restrict__ rowptr,
                                              const int2* __restrict__ pairs,
                                              float* __restrict__ dinv2, int N) {
    int n = blockIdx.x * 256 + threadIdx.x;
    if (n >= N) return;
    int s = rowptr[n], e = rowptr[n + 1];
    float a = 1.f;
    for (int p = s; p < e; ++p) a += __int_as_float(pairs[p].y);
    dinv2[n] = rsqrtf(a);
}

// ======== g1 = bf16( dinv2 * (x @ W1) ) via MFMA 16x16x32 bf16 ========
__global__ __launch_bounds__(256) void k_mm1(const float* __restrict__ x,
                                             const unsigned short* __restrict__ W1t,
                                             const float* __restrict__ dinv2,
                                             unsigned short* __restrict__ gbuf, int N) {
    __shared__ __align__(16) unsigned short xb[64 * FIN];   // 16 KiB
    int tid  = threadIdx.x;
    int lane = tid & 63;
    int w    = tid >> 6;
    int lrow = lane & 15;
    int lk8  = lane >> 4;          // 0..3
    int tile0 = blockIdx.x * 64;
    if (tile0 >= N) return;
    int nrow = min(64, N - tile0);

    short8v breg[4][4];
    #pragma unroll
    for (int kk = 0; kk < 4; ++kk)
        #pragma unroll
        for (int ct = 0; ct < 4; ++ct)
            breg[kk][ct] = *(const short8v*)(W1t + (16 * ct + lrow) * FIN + kk * 32 + lk8 * 8);

    const float4* gx = (const float4*)(x + (size_t)tile0 * FIN);
    int nv = nrow * (FIN / 4);
    for (int i = tid; i < nv; i += 256) {
        float4 v = gx[i];
        int row = i >> 5;                      // FIN/4 = 32 float4 per row
        int byte = row * 256 + (i & 31) * 8;
        unsigned swz = (unsigned)(byte ^ ((row & 7) << 4));
        *(uint2*)((char*)xb + swz) = make_uint2(pack2(v.x, v.y), pack2(v.z, v.w));
    }
    __syncthreads();

    f32x4 acc[4];
    #pragma unroll
    for (int ct = 0; ct < 4; ++ct) acc[ct] = 0.f;
    int arow = 16 * w + lrow;
    #pragma unroll
    for (int kk = 0; kk < 4; ++kk) {
        int byte = arow * 256 + kk * 64 + lk8 * 16;
        unsigned swz = (unsigned)(byte ^ ((arow & 7) << 4));
        short8v a = *(const short8v*)((const char*)xb + swz);
        #pragma unroll
        for (int ct = 0; ct < 4; ++ct)
            acc[ct] = __builtin_amdgcn_mfma_f32_16x16x32_bf16(a, breg[kk][ct], acc[ct], 0, 0, 0);
    }
    #pragma unroll
    for (int i = 0; i < 4; ++i) {
        int grow = tile0 + 16 * w + lk8 * 4 + i;
        if (grow < N) {
            float sn = dinv2[grow];
            #pragma unroll
            for (int ct = 0; ct < 4; ++ct)
                gbuf[(size_t)grow * HD + 16 * ct + lrow] = f2bf(sn * acc[ct][i]);
        }
    }
}

// ======== g2 = bf16( dinv2 * (relu(agg+b1) @ W2) ) via MFMA, K=64 ========
__global__ __launch_bounds__(256) void k_mm2(const float* __restrict__ agg,
                                             const float* __restrict__ b1,
                                             const unsigned short* __restrict__ W2t,
                                             const float* __restrict__ dinv2,
                                             unsigned short* __restrict__ gbuf, int N) {
    __shared__ __align__(16) unsigned short xb[64 * HD];    // 8 KiB
    int tid  = threadIdx.x;
    int lane = tid & 63;
    int w    = tid >> 6;
    int lrow = lane & 15;
    int lk8  = lane >> 4;
    int tile0 = blockIdx.x * 64;
    if (tile0 >= N) return;
    int nrow = min(64, N - tile0);

    short8v breg[2][4];
    #pragma unroll
    for (int kk = 0; kk < 2; ++kk)
        #pragma unroll
        for (int ct = 0; ct < 4; ++ct)
            breg[kk][ct] = *(const short8v*)(W2t + (16 * ct + lrow) * HD + kk * 32 + lk8 * 8);

    const float4* gx = (const float4*)(agg + (size_t)tile0 * HD);
    const float4* bf4 = (const float4*)b1;
    int nv = nrow * (HD / 4);
    for (int i = tid; i < nv; i += 256) {
        float4 v = gx[i];
        float4 bb = bf4[i & 15];
        v.x = fmaxf(v.x + bb.x, 0.f);
        v.y = fmaxf(v.y + bb.y, 0.f);
        v.z = fmaxf(v.z + bb.z, 0.f);
        v.w = fmaxf(v.w + bb.w, 0.f);
        int row = i >> 4;                      // HD/4 = 16 float4 per row
        int byte = row * 128 + (i & 15) * 8;
        unsigned swz = (unsigned)(byte ^ ((row & 7) << 4));
        *(uint2*)((char*)xb + swz) = make_uint2(pack2(v.x, v.y), pack2(v.z, v.w));
    }
    __syncthreads();

    f32x4 acc[4];
    #pragma unroll
    for (int ct = 0; ct < 4; ++ct) acc[ct] = 0.f;
    int arow = 16 * w + lrow;
    #pragma unroll
    for (int kk = 0; kk < 2; ++kk) {
        int byte = arow * 128 + kk * 64 + lk8 * 16;
        unsigned swz = (unsigned)(byte ^ ((arow & 7) << 4));
        short8v a = *(const short8v*)((const char*)xb + swz);
        #pragma unroll
        for (int ct = 0; ct < 4; ++ct)
            acc[ct] = __builtin_amdgcn_mfma_f32_16x16x32_bf16(a, breg[kk][ct], acc[ct], 0, 0, 0);
    }
    #pragma unroll
    for (int i = 0; i < 4; ++i) {
        int grow = tile0 + 16 * w + lk8 * 4 + i;
        if (grow < N) {
            float sn = dinv2[grow];
            #pragma unroll
            for (int ct = 0; ct < 4; ++ct)
                gbuf[(size_t)grow * HD + 16 * ct + lrow] = f2bf(sn * acc[ct][i]);
        }
    }
}

// ------- CSR gather, software-pipelined batch-8 (round-13 verbatim: measured 59.3 us) -------
__global__ __launch_bounds__(256) void k_agg(const int* __restrict__ rowptr,
                                             const int2* __restrict__ pairs,
                                             const unsigned short* __restrict__ g,
                                             const float* __restrict__ dinv2,
                                             float* __restrict__ agg, int N) {
    int lane = threadIdx.x & 63;
    int node = (blockIdx.x * 256 + threadIdx.x) >> 6;
    if (node >= N) return;
    int s = rowptr[node];
    int e = rowptr[node + 1];
    float a0 = bf2f(g[(size_t)node * HD + lane]);
    float a1 = 0.f, a2 = 0.f, a3 = 0.f;
    int p = s;
    int nb = (e - s) >> 3;                       // full 8-batches
    if (nb > 0) {
        int2 prA[8], prB[8];
        #pragma unroll
        for (int j = 0; j < 8; ++j) prA[j] = pairs[p + j];       // prologue
        for (int b = 0; b < nb; ++b) {
            if (b + 1 < nb) {
                #pragma unroll
                for (int j = 0; j < 8; ++j) prB[j] = pairs[p + 8 + j];   // prefetch next
            }
            float v[8];
            #pragma unroll
            for (int j = 0; j < 8; ++j)                          // 8 indep gathers
                v[j] = bf2f(g[(size_t)prA[j].x * HD + lane]);
            a0 += __int_as_float(prA[0].y) * v[0] + __int_as_float(prA[4].y) * v[4];
            a1 += __int_as_float(prA[1].y) * v[1] + __int_as_float(prA[5].y) * v[5];
            a2 += __int_as_float(prA[2].y) * v[2] + __int_as_float(prA[6].y) * v[6];
            a3 += __int_as_float(prA[3].y) * v[3] + __int_as_float(prA[7].y) * v[7];
            #pragma unroll
            for (int j = 0; j < 8; ++j) prA[j] = prB[j];         // rotate buffers
            p += 8;
        }
    }
    if (p + 4 <= e) {
        int2 pr[4];
        #pragma unroll
        for (int j = 0; j < 4; ++j) pr[j] = pairs[p + j];
        float v[4];
        #pragma unroll
        for (int j = 0; j < 4; ++j)
            v[j] = bf2f(g[(size_t)pr[j].x * HD + lane]);
        a0 += __int_as_float(pr[0].y) * v[0];
        a1 += __int_as_float(pr[1].y) * v[1];
        a2 += __int_as_float(pr[2].y) * v[2];
        a3 += __int_as_float(pr[3].y) * v[3];
        p += 4;
    }
    for (; p < e; ++p) {
        int2 pr = pairs[p];
        a0 += __int_as_float(pr.y) * bf2f(g[(size_t)pr.x * HD + lane]);
    }
    agg[(size_t)node * HD + lane] = dinv2[node] * ((a0 + a1) + (a2 + a3));
}

// ---------------- out = relu(agg + b2) @ Wout + bout ----------------
__global__ __launch_bounds__(256) void k_out(const float* __restrict__ agg,
                                             const float* __restrict__ b2,
                                             const float* __restrict__ Wout,
                                             const float* __restrict__ bout,
                                             float* __restrict__ out, int N) {
    __shared__ float Wl[HD * TD];
    __shared__ float bl[HD];
    __shared__ float bo[TD];
    for (int i = threadIdx.x; i < HD * TD; i += 256) Wl[i] = Wout[i];
    if (threadIdx.x < HD) bl[threadIdx.x] = b2[threadIdx.x];
    if (threadIdx.x < TD) bo[threadIdx.x] = bout[threadIdx.x];
    __syncthreads();
    int idx = blockIdx.x * 256 + threadIdx.x;
    if (idx >= N * TD) return;
    int n = idx / TD;
    int t = idx - n * TD;
    const float* a = agg + (size_t)n * HD;
    float acc = bo[t];
    #pragma unroll 8
    for (int k = 0; k < HD; ++k)
        acc += fmaxf(a[k] + bl[k], 0.f) * Wl[k * TD + t];
    out[idx] = acc;
}

extern "C" void kernel_launch(void* const* d_in, const int* in_sizes, int n_in,
                              void* d_out, int out_size, void* d_ws, size_t ws_size,
                              hipStream_t stream) {
    const float* x    = (const float*)d_in[0];
    const int*   ei   = (const int*)d_in[1];   // harness passes integers as int32
    const float* et   = (const float*)d_in[2];
    const float* W1   = (const float*)d_in[3];
    const float* b1   = (const float*)d_in[4];
    const float* W2   = (const float*)d_in[5];
    const float* b2   = (const float*)d_in[6];
    const float* Wout = (const float*)d_in[7];
    const float* bout = (const float*)d_in[8];
    float*       out  = (float*)d_out;

    int N = in_sizes[0] / FIN;
    int E = in_sizes[2];
    int NCHUNK_F = (N + CHUNK - 1) / CHUNK;        // 7 fill chunks
    int NCHUNK_D = (N + CHUNK_D - 1) / CHUNK_D;    // 4 deg/hist super-chunks
    int NB = (N + SCAN_ELEMS - 1) / SCAN_ELEMS;    // scan blocks (98)

    // --- workspace layout, 256B-aligned regions, with lifetime aliasing ---
    char*  base = (char*)d_ws;
    size_t ofs  = 0;
    auto alloc = [&](size_t bytes) -> char* {
        char* p = base + ofs;
        ofs = (ofs + bytes + 255) & ~(size_t)255;
        return p;
    };
    unsigned*       tmaxb = (unsigned*)alloc(64);
    unsigned short* W1t   = (unsigned short*)alloc((size_t)FIN * HD * 2);
    unsigned short* W2t   = (unsigned short*)alloc((size_t)HD * HD * 2);
    float*    ebuf   = (float*)alloc((size_t)E * 4);        // decay
    float*    dinv   = (float*)alloc((size_t)N * 4);
    float*    dinv2  = (float*)alloc((size_t)N * 4);
    int*      hist   = (int*)alloc((size_t)N * 4);
    int*      rowptr = (int*)alloc((size_t)(N + 1) * 4);
    int*      bsum   = (int*)alloc((size_t)1024 * 4);
    int*      boff   = (int*)alloc((size_t)1024 * 4);

    size_t privDBytes = (size_t)NCHUNK_D * SPLIT * CHUNK_D * 4;      // 33.6 MB
    size_t pairBytes  = (((size_t)E * 8) + 255) & ~(size_t)255;      // 12.8 MB
    size_t gbufBytes  = (size_t)N * HD * 2;                          // 12.8 MB
    size_t regionX = privDBytes > pairBytes + gbufBytes ? privDBytes : pairBytes + gbufBytes;
    char* X = alloc(regionX);
    float*          privD = (float*)X;                 // live k_deg -> k_red
    int2*           pairs = (int2*)X;                  // live k_fill -> end
    unsigned short* gbuf  = (unsigned short*)(X + pairBytes);  // live k_mm1 -> end

    size_t privHBytes = (size_t)NCHUNK_D * 2 * SPLIT * CHUNK * 2;    // 16.8 MB (8 fill-chunks)
    size_t aggBytes   = (size_t)N * HD * 4;                          // 25.6 MB
    size_t regionY = privHBytes > aggBytes ? privHBytes : aggBytes;
    char* Y = alloc(regionY);
    unsigned short* privH = (unsigned short*)Y;        // live k_hist -> k_fill
    float*          agg   = (float*)Y;                 // live k_agg -> end

    int bN  = (N + 255) / 256;
    int bT  = (N + 63) / 64;
    int bWN = (N * HD + 255) / 256;
    int bD  = NCHUNK_D * SPLIT;                        // 256 deg/hist blocks
    int bF  = NCHUNK_F * SPLIT;                        // 448 fill blocks

    k_cvtW  <<<32,  256, 0, stream>>>(W1, W2, W1t, W2t, tmaxb);
    k_tmax  <<<256, 256, 0, stream>>>(et, tmaxb, E);
    k_deg   <<<bD, 1024, 0, stream>>>(ei, et, tmaxb, ebuf, privD, E, N);
    k_hist  <<<bD, 1024, 0, stream>>>(ei, privH, E, N);
    k_red   <<<bN,  256, 0, stream>>>(privD, privH, dinv, hist, N);
    k_scan_a<<<NB,  256, 0, stream>>>(hist, bsum, N);
    k_scan_b<<<1,  1024, 0, stream>>>(bsum, boff, NB, rowptr + N);
    k_scan_c<<<NB,  256, 0, stream>>>(hist, boff, rowptr, N);
    k_fill  <<<bF, 1024, 0, stream>>>(ei, ebuf, dinv, rowptr, privH, pairs, E, N);
    k_deg2  <<<bN,  256, 0, stream>>>(rowptr, pairs, dinv2, N);

    k_mm1   <<<bT,  256, 0, stream>>>(x, W1t, dinv2, gbuf, N);
    k_agg   <<<bWN, 256, 0, stream>>>(rowptr, pairs, gbuf, dinv2, agg, N);
    k_mm2   <<<bT,  256, 0, stream>>>(agg, b1, W2t, dinv2, gbuf, N);
    k_agg   <<<bWN, 256, 0, stream>>>(rowptr, pairs, gbuf, dinv2, agg, N);
    k_out   <<<(N * TD + 255) / 256, 256, 0, stream>>>(agg, b2, Wout, bout, out, N);
}